// Round 11
// baseline (5013.885 us; speedup 1.0000x reference)
//
#include <hip/hip_runtime.h>
#include <hip/hip_bf16.h>

// SSNet: 2-layer flag-gated LSTM, persistent-tile MFMA implementation.
// B=16384, T=32, IN=64, H=512, OUT=19.
// R11 = R10 geometry (512 thr / 8 waves / VGPR=128 / 4-row-reuse B tile)
// with L1(t) and L0(t+1) merged into ONE barrier interval: both read only
// interval-stable LDS (h0s=h0(t), h1s=h1(t-1), xs=x(t+1)), so per step
// there is 1 __syncthreads + 1 combined refill instead of 2+2. Double
// flag buffer (flags0=flag(t), flags1=flag(t+1)) rotated in the refill.
// Final linear reads fp32 h1(31) directly from hws1 (no last refill).

#define T_STEPS 32
#define IN_F    64
#define HID     512
#define OUT_F   19
#define BW      64   // batch rows per WG

typedef short bf16x8 __attribute__((ext_vector_type(8)));   // 8 bf16 = 4 VGPRs
typedef float f32x4  __attribute__((ext_vector_type(4)));

__device__ __forceinline__ float fast_sig(float x) {
    return __builtin_amdgcn_rcpf(1.0f + __expf(-x));
}
__device__ __forceinline__ float fast_tanh(float x) {
    return 1.0f - 2.0f * __builtin_amdgcn_rcpf(1.0f + __expf(2.0f * x));
}

// Light barrier: LDS hazards only (don't drain vmcnt).
#define LBAR() do { \
    asm volatile("s_waitcnt lgkmcnt(0)" ::: "memory"); \
    __builtin_amdgcn_sched_barrier(0); \
    __builtin_amdgcn_s_barrier(); \
    __builtin_amdgcn_sched_barrier(0); \
} while (0)

// 4 row-tiles x 4 gates
#define MFMA16(A0, A1, A2, A3, Q0, Q1, Q2, Q3) do { \
    acc[0][0] = __builtin_amdgcn_mfma_f32_16x16x32_bf16(A0, Q0, acc[0][0], 0, 0, 0); \
    acc[1][0] = __builtin_amdgcn_mfma_f32_16x16x32_bf16(A1, Q0, acc[1][0], 0, 0, 0); \
    acc[2][0] = __builtin_amdgcn_mfma_f32_16x16x32_bf16(A2, Q0, acc[2][0], 0, 0, 0); \
    acc[3][0] = __builtin_amdgcn_mfma_f32_16x16x32_bf16(A3, Q0, acc[3][0], 0, 0, 0); \
    acc[0][1] = __builtin_amdgcn_mfma_f32_16x16x32_bf16(A0, Q1, acc[0][1], 0, 0, 0); \
    acc[1][1] = __builtin_amdgcn_mfma_f32_16x16x32_bf16(A1, Q1, acc[1][1], 0, 0, 0); \
    acc[2][1] = __builtin_amdgcn_mfma_f32_16x16x32_bf16(A2, Q1, acc[2][1], 0, 0, 0); \
    acc[3][1] = __builtin_amdgcn_mfma_f32_16x16x32_bf16(A3, Q1, acc[3][1], 0, 0, 0); \
    acc[0][2] = __builtin_amdgcn_mfma_f32_16x16x32_bf16(A0, Q2, acc[0][2], 0, 0, 0); \
    acc[1][2] = __builtin_amdgcn_mfma_f32_16x16x32_bf16(A1, Q2, acc[1][2], 0, 0, 0); \
    acc[2][2] = __builtin_amdgcn_mfma_f32_16x16x32_bf16(A2, Q2, acc[2][2], 0, 0, 0); \
    acc[3][2] = __builtin_amdgcn_mfma_f32_16x16x32_bf16(A3, Q2, acc[3][2], 0, 0, 0); \
    acc[0][3] = __builtin_amdgcn_mfma_f32_16x16x32_bf16(A0, Q3, acc[0][3], 0, 0, 0); \
    acc[1][3] = __builtin_amdgcn_mfma_f32_16x16x32_bf16(A1, Q3, acc[1][3], 0, 0, 0); \
    acc[2][3] = __builtin_amdgcn_mfma_f32_16x16x32_bf16(A2, Q3, acc[2][3], 0, 0, 0); \
    acc[3][3] = __builtin_amdgcn_mfma_f32_16x16x32_bf16(A3, Q3, acc[3][3], 0, 0, 0); \
} while (0)

// Packed B layout, per 16-col block cb of the 2048 gate-cols:
//   dst[cb*(K*16) + kc*512 + l15*32 + lq*8 + e] = W[kc*32+lq*8+e + rowOff][cb*16+l15]
__global__ void wprep_kernel(const float* __restrict__ src,
                             __hip_bfloat16* __restrict__ dst,
                             int kcBits, int rowOff) {
    int idx = blockIdx.x * 256 + threadIdx.x;
    int total = 2048 << (kcBits + 5);
    if (idx >= total) return;
    int e   = idx & 7;
    int lq  = (idx >> 3) & 3;
    int l15 = (idx >> 5) & 15;
    int kc  = (idx >> 9) & ((1 << kcBits) - 1);
    int cb  = idx >> (9 + kcBits);
    int k   = kc * 32 + lq * 8 + e + rowOff;
    int col = cb * 16 + l15;
    dst[idx] = __float2bfloat16(src[(size_t)k * 2048 + col]);
}

// KC chunks, depth-2 rotated B pipeline, 4 row-tiles (stride RTS bytes).
template<int KC, int RTS>
__device__ __forceinline__ void gemm_sec4(const char* aE, const char* aO,
                                          const __hip_bfloat16* b0p,
                                          const __hip_bfloat16* b1p,
                                          const __hip_bfloat16* b2p,
                                          const __hip_bfloat16* b3p,
                                          f32x4 acc[4][4]) {
    bf16x8 pa0, pa1, pa2, pa3, pb0, pb1, pb2, pb3, a0, a1, a2, a3;
    pa0 = *(const bf16x8*)(b0p);
    pa1 = *(const bf16x8*)(b1p);
    pa2 = *(const bf16x8*)(b2p);
    pa3 = *(const bf16x8*)(b3p);
    #pragma unroll 1
    for (int m = 0; m < KC - 2; m += 2) {
        const int ao = (m >> 1) * 128;
        pb0 = *(const bf16x8*)(b0p + (m + 1) * 512);
        pb1 = *(const bf16x8*)(b1p + (m + 1) * 512);
        pb2 = *(const bf16x8*)(b2p + (m + 1) * 512);
        pb3 = *(const bf16x8*)(b3p + (m + 1) * 512);
        a0 = *(const bf16x8*)(aE + ao);
        a1 = *(const bf16x8*)(aE + RTS + ao);
        a2 = *(const bf16x8*)(aE + 2 * RTS + ao);
        a3 = *(const bf16x8*)(aE + 3 * RTS + ao);
        MFMA16(a0, a1, a2, a3, pa0, pa1, pa2, pa3);
        pa0 = *(const bf16x8*)(b0p + (m + 2) * 512);
        pa1 = *(const bf16x8*)(b1p + (m + 2) * 512);
        pa2 = *(const bf16x8*)(b2p + (m + 2) * 512);
        pa3 = *(const bf16x8*)(b3p + (m + 2) * 512);
        a0 = *(const bf16x8*)(aO + ao);
        a1 = *(const bf16x8*)(aO + RTS + ao);
        a2 = *(const bf16x8*)(aO + 2 * RTS + ao);
        a3 = *(const bf16x8*)(aO + 3 * RTS + ao);
        MFMA16(a0, a1, a2, a3, pb0, pb1, pb2, pb3);
    }
    {   // tail: chunks KC-2 (in pa) and KC-1
        const int ao = ((KC - 2) >> 1) * 128;
        pb0 = *(const bf16x8*)(b0p + (KC - 1) * 512);
        pb1 = *(const bf16x8*)(b1p + (KC - 1) * 512);
        pb2 = *(const bf16x8*)(b2p + (KC - 1) * 512);
        pb3 = *(const bf16x8*)(b3p + (KC - 1) * 512);
        a0 = *(const bf16x8*)(aE + ao);
        a1 = *(const bf16x8*)(aE + RTS + ao);
        a2 = *(const bf16x8*)(aE + 2 * RTS + ao);
        a3 = *(const bf16x8*)(aE + 3 * RTS + ao);
        MFMA16(a0, a1, a2, a3, pa0, pa1, pa2, pa3);
        a0 = *(const bf16x8*)(aO + ao);
        a1 = *(const bf16x8*)(aO + RTS + ao);
        a2 = *(const bf16x8*)(aO + 2 * RTS + ao);
        a3 = *(const bf16x8*)(aO + 3 * RTS + ao);
        MFMA16(a0, a1, a2, a3, pb0, pb1, pb2, pb3);
    }
}

__global__ __launch_bounds__(512, 2)
void lstm_main(const float* __restrict__ x,
               const float* __restrict__ b0v,
               const float* __restrict__ Wx1,     // row 0 = flag weights (f32)
               const float* __restrict__ b1v,
               const float* __restrict__ Wlin,
               const float* __restrict__ blin,
               const __hip_bfloat16* __restrict__ Wx0p,
               const __hip_bfloat16* __restrict__ Wh0p,
               const __hip_bfloat16* __restrict__ Wx1hp,
               const __hip_bfloat16* __restrict__ Wh1p,
               float* __restrict__ cws,
               float* __restrict__ hws,
               float* __restrict__ out)
{
    // LDS h tiles: row-major bf16, row stride 1024B, XOR-swizzle (row&7)<<4
    __shared__ __align__(16) __hip_bfloat16 h0s[BW * HID];   // 64 KB
    __shared__ __align__(16) __hip_bfloat16 h1s[BW * HID];   // 64 KB
    __shared__ __align__(16) __hip_bfloat16 xs[BW * IN_F];   // 8 KB, row stride 128B
    __shared__ float flags0[BW];   // flag(t)   -> L1(t) blend
    __shared__ float flags1[BW];   // flag(t+1) -> L0(t+1) blend

    const int tid  = threadIdx.x;
    const int lane = tid & 63;
    const int wid  = tid >> 6;      // 0..7
    const int l15  = lane & 15;
    const int lq   = lane >> 4;
    const int lq16 = lq * 16;
    const int laneoff = l15 * 32 + lq * 8;
    const int asw  = (l15 & 7) << 4;
    const int wg   = blockIdx.x;
    const size_t bbase = (size_t)wg * BW;
    const char* xsC = (const char*)xs;
    const char* h0C = (const char*)h0s;

    const int swE = lq16 ^ asw;
    const int swO = (64 + lq16) ^ asw;
    const char* ahE = h0C + l15 * 1024 + swE;
    const char* ahO = h0C + l15 * 1024 + swO;
    const int h1d = (int)((const char*)h1s - (const char*)h0s);
    const char* axE = xsC + l15 * 128 + swE;
    const char* axO = xsC + l15 * 128 + swO;

    const size_t wsWG0 = (size_t)(0 * 256 + wg) * 32768;   // floats
    const size_t wsWG1 = (size_t)(1 * 256 + wg) * 32768;

    // ---- Layer-1 phase: g1 = flag*Wx1[0] + h0s@Wx1h + h1s@Wh1 + b1 ----
    auto do_L1 = [&](bool zstate) {
        #pragma unroll 1
        for (int sb = 0; sb < 4; ++sb) {
            const int b2 = sb * 8 + wid;
            f32x4 acc[4][4];
            { f32x4 zz = {0.f, 0.f, 0.f, 0.f};
              #pragma unroll
              for (int rt = 0; rt < 4; ++rt)
                  #pragma unroll
                  for (int g = 0; g < 4; ++g) acc[rt][g] = zz; }

            gemm_sec4<16, 16384>(ahE, ahO,
                Wx1hp + (size_t)(0 * 32 + b2) * 8192 + laneoff,
                Wx1hp + (size_t)(1 * 32 + b2) * 8192 + laneoff,
                Wx1hp + (size_t)(2 * 32 + b2) * 8192 + laneoff,
                Wx1hp + (size_t)(3 * 32 + b2) * 8192 + laneoff, acc);
            gemm_sec4<16, 16384>(ahE + h1d, ahO + h1d,
                Wh1p + (size_t)(0 * 32 + b2) * 8192 + laneoff,
                Wh1p + (size_t)(1 * 32 + b2) * 8192 + laneoff,
                Wh1p + (size_t)(2 * 32 + b2) * 8192 + laneoff,
                Wh1p + (size_t)(3 * 32 + b2) * 8192 + laneoff, acc);

            const size_t sbase = wsWG1 + (size_t)b2 * 1024 + lane * 4;
            const int jcol = b2 * 16 + l15;
            float bia[4], w10[4];
            #pragma unroll
            for (int g = 0; g < 4; ++g) {
                bia[g] = b1v[g * 512 + jcol];
                w10[g] = Wx1[g * 512 + jcol];
            }
            #pragma unroll
            for (int rt = 0; rt < 4; ++rt) {
                f32x4 cold, hold;
                if (!zstate) {
                    cold = __builtin_nontemporal_load((const f32x4*)(cws + sbase + rt * 256));
                    hold = *(const f32x4*)(hws + sbase + rt * 256);
                } else {
                    f32x4 zz = {0.f, 0.f, 0.f, 0.f}; cold = zz; hold = zz;
                }
                f32x4 cnew, hnew;
                #pragma unroll
                for (int r = 0; r < 4; ++r) {
                    const float f = flags0[rt * 16 + lq * 4 + r];
                    float gi = acc[rt][0][r] + bia[0] + f * w10[0];
                    float gf = acc[rt][1][r] + bia[1] + f * w10[1];
                    float gg = acc[rt][2][r] + bia[2] + f * w10[2];
                    float go = acc[rt][3][r] + bia[3] + f * w10[3];
                    float cn = fast_sig(gf) * cold[r] + fast_sig(gi) * fast_tanh(gg);
                    float hn = fast_sig(go) * fast_tanh(cn);
                    cnew[r] = f * cn + (1.f - f) * cold[r];
                    hnew[r] = f * hn + (1.f - f) * hold[r];
                }
                __builtin_nontemporal_store(cnew, (f32x4*)(cws + sbase + rt * 256));
                *(f32x4*)(hws + sbase + rt * 256) = hnew;
            }
        }
    };

    // ---- Layer-0 phase: g0 = xs@Wx0 + h0s@Wh0 + b0 (blend with flags1) ----
    auto do_L0 = [&](bool zstate) {
        #pragma unroll 1
        for (int sb = 0; sb < 4; ++sb) {
            const int b2 = sb * 8 + wid;
            f32x4 acc[4][4];
            { f32x4 zz = {0.f, 0.f, 0.f, 0.f};
              #pragma unroll
              for (int rt = 0; rt < 4; ++rt)
                  #pragma unroll
                  for (int g = 0; g < 4; ++g) acc[rt][g] = zz; }

            {   // x part: 2 chunks straight-line
                const __hip_bfloat16* bx0 = Wx0p + (size_t)(0 * 32 + b2) * 1024 + laneoff;
                const __hip_bfloat16* bx1 = Wx0p + (size_t)(1 * 32 + b2) * 1024 + laneoff;
                const __hip_bfloat16* bx2 = Wx0p + (size_t)(2 * 32 + b2) * 1024 + laneoff;
                const __hip_bfloat16* bx3 = Wx0p + (size_t)(3 * 32 + b2) * 1024 + laneoff;
                bf16x8 pa0 = *(const bf16x8*)(bx0);
                bf16x8 pa1 = *(const bf16x8*)(bx1);
                bf16x8 pa2 = *(const bf16x8*)(bx2);
                bf16x8 pa3 = *(const bf16x8*)(bx3);
                bf16x8 pb0 = *(const bf16x8*)(bx0 + 512);
                bf16x8 pb1 = *(const bf16x8*)(bx1 + 512);
                bf16x8 pb2 = *(const bf16x8*)(bx2 + 512);
                bf16x8 pb3 = *(const bf16x8*)(bx3 + 512);
                bf16x8 a0 = *(const bf16x8*)(axE);
                bf16x8 a1 = *(const bf16x8*)(axE + 2048);
                bf16x8 a2 = *(const bf16x8*)(axE + 4096);
                bf16x8 a3 = *(const bf16x8*)(axE + 6144);
                MFMA16(a0, a1, a2, a3, pa0, pa1, pa2, pa3);
                a0 = *(const bf16x8*)(axO);
                a1 = *(const bf16x8*)(axO + 2048);
                a2 = *(const bf16x8*)(axO + 4096);
                a3 = *(const bf16x8*)(axO + 6144);
                MFMA16(a0, a1, a2, a3, pb0, pb1, pb2, pb3);
            }
            gemm_sec4<16, 16384>(ahE, ahO,
                Wh0p + (size_t)(0 * 32 + b2) * 8192 + laneoff,
                Wh0p + (size_t)(1 * 32 + b2) * 8192 + laneoff,
                Wh0p + (size_t)(2 * 32 + b2) * 8192 + laneoff,
                Wh0p + (size_t)(3 * 32 + b2) * 8192 + laneoff, acc);

            const size_t sbase = wsWG0 + (size_t)b2 * 1024 + lane * 4;
            const int jcol = b2 * 16 + l15;
            float bia[4];
            #pragma unroll
            for (int g = 0; g < 4; ++g) bia[g] = b0v[g * 512 + jcol];
            #pragma unroll
            for (int rt = 0; rt < 4; ++rt) {
                f32x4 cold, hold;
                if (!zstate) {
                    cold = __builtin_nontemporal_load((const f32x4*)(cws + sbase + rt * 256));
                    hold = *(const f32x4*)(hws + sbase + rt * 256);
                } else {
                    f32x4 zz = {0.f, 0.f, 0.f, 0.f}; cold = zz; hold = zz;
                }
                f32x4 cnew, hnew;
                #pragma unroll
                for (int r = 0; r < 4; ++r) {
                    const float f = flags1[rt * 16 + lq * 4 + r];
                    float gi = acc[rt][0][r] + bia[0];
                    float gf = acc[rt][1][r] + bia[1];
                    float gg = acc[rt][2][r] + bia[2];
                    float go = acc[rt][3][r] + bia[3];
                    float cn = fast_sig(gf) * cold[r] + fast_sig(gi) * fast_tanh(gg);
                    float hn = fast_sig(go) * fast_tanh(cn);
                    cnew[r] = f * cn + (1.f - f) * cold[r];
                    hnew[r] = f * hn + (1.f - f) * hold[r];
                }
                __builtin_nontemporal_store(cnew, (f32x4*)(cws + sbase + rt * 256));
                *(f32x4*)(hws + sbase + rt * 256) = hnew;
            }
        }
    };

    auto refill = [&](__hip_bfloat16* dst, size_t wsWG) {
        for (int i4 = tid; i4 < BW * HID / 4; i4 += 512) {
            f32x4 v = *(const f32x4*)(hws + wsWG + (size_t)i4 * 4);
            int lane2 = i4 & 63, rt2 = (i4 >> 6) & 3, b2r = i4 >> 8;
            int col2 = 2 * (b2r * 16 + (lane2 & 15));
            int rowb = rt2 * 16 + (lane2 >> 4) * 4;
            #pragma unroll
            for (int r = 0; r < 4; ++r) {
                int row = rowb + r;
                int byte = row * 1024 + (col2 ^ ((row & 7) << 4));
                *(__hip_bfloat16*)((char*)dst + byte) = __float2bfloat16(v[r]);
            }
        }
    };

    auto stage_x = [&](int tt) {
        for (int i = tid; i < BW * IN_F; i += 512) {
            int row = i >> 6, k = i & 63;
            float v = __builtin_nontemporal_load(&x[(bbase + row) * (T_STEPS * IN_F) + tt * IN_F + k]);
            int byte = row * 128 + ((2 * k) ^ ((row & 7) << 4));
            *(__hip_bfloat16*)((char*)xs + byte) = __float2bfloat16(v);
        }
    };

    // ================= prologue =================
    {
        int4 z; z.x = z.y = z.z = z.w = 0;
        int4* p0 = (int4*)h0s; int4* p1 = (int4*)h1s;
        for (int i = tid; i < BW * HID * 2 / 16; i += 512) { p0[i] = z; p1[i] = z; }
    }
    stage_x(0);
    if (tid < BW) {
        float f0 = x[(bbase + tid) * (T_STEPS * IN_F)];
        flags0[tid] = f0;
        flags1[tid] = f0;      // prologue do_L0 uses flags1 = flag(0)
    }
    LBAR();

    do_L0(true);               // L0(0): h0s is zero, state zero
    __syncthreads();
    refill(h0s, wsWG0);        // h0s <- h0(0)
    stage_x(1);                // xs <- x(1)
    if (tid < BW) flags1[tid] = x[(bbase + tid) * (T_STEPS * IN_F) + IN_F];  // flag(1)
    LBAR();

    // ================= main loop: intervals t = 0..30 =================
    #pragma unroll 1
    for (int t = 0; t < T_STEPS - 1; ++t) {
        do_L1(t == 0);         // L1(t): h0s=h0(t), h1s=h1(t-1), flags0=flag(t)
        do_L0(false);          // L0(t+1): xs=x(t+1), h0s=h0(t), flags1=flag(t+1)
        __syncthreads();       // hws0/hws1 complete; LDS reads done
        refill(h0s, wsWG0);    // h0s <- h0(t+1)
        refill(h1s, wsWG1);    // h1s <- h1(t)
        if (tid < BW) {
            float f1 = flags1[tid];
            flags0[tid] = f1;  // flag(t+1) becomes current
            flags1[tid] = (t + 2 < T_STEPS)
                ? x[(bbase + tid) * (T_STEPS * IN_F) + (size_t)(t + 2) * IN_F] : 0.f;
        }
        if (t + 2 < T_STEPS) stage_x(t + 2);
        LBAR();
    }

    // ================= epilogue: L1(31) =================
    do_L1(false);              // flags0 = flag(31)
    __syncthreads();           // hws1 = fp32 h1(31)

    // ---- final linear from fp32 hws1: out = h1 @ Wlin + blin ----
    for (int task = tid; task < BW * OUT_F; task += 512) {
        int o   = task >> 6;     // 0..18, wave-uniform
        int row = task & 63;
        const int base_row = ((row >> 4) << 8) + (((row >> 2) & 3) << 6) + (row & 3);
        float s = blin[o];
        const float* hp = hws + wsWG1 + base_row;
        const float* wl = Wlin + o;
        #pragma unroll 1
        for (int kb = 0; kb < 32; ++kb) {
            #pragma unroll
            for (int kl = 0; kl < 16; ++kl)
                s += hp[kb * 1024 + kl * 4] * wl[(kb * 16 + kl) * OUT_F];
        }
        out[(bbase + row) * OUT_F + o] = s;
    }
}

extern "C" void kernel_launch(void* const* d_in, const int* in_sizes, int n_in,
                              void* d_out, int out_size, void* d_ws, size_t ws_size,
                              hipStream_t stream) {
    const float* x    = (const float*)d_in[0];
    const float* Wx0  = (const float*)d_in[1];
    const float* Wh0  = (const float*)d_in[2];
    const float* b0   = (const float*)d_in[3];
    const float* Wx1  = (const float*)d_in[4];
    const float* Wh1  = (const float*)d_in[5];
    const float* b1   = (const float*)d_in[6];
    const float* Wlin = (const float*)d_in[7];
    const float* blin = (const float*)d_in[8];

    // workspace carve (bytes)
    const size_t offWx0p  = 0;                       // 2048*64*2   = 262144
    const size_t offWh0p  = 262144;                  // 2048*512*2  = 2097152
    const size_t offWx1hp = 2359296;
    const size_t offWh1p  = 4456448;
    const size_t offC     = 6553600;                 // 2*256*32768*4 = 67108864
    const size_t offH     = 73662464;                // 67108864
    const size_t needed   = 140771328;
    if (ws_size < needed) return;

    char* w = (char*)d_ws;
    __hip_bfloat16* Wx0p  = (__hip_bfloat16*)(w + offWx0p);
    __hip_bfloat16* Wh0p  = (__hip_bfloat16*)(w + offWh0p);
    __hip_bfloat16* Wx1hp = (__hip_bfloat16*)(w + offWx1hp);
    __hip_bfloat16* Wh1p  = (__hip_bfloat16*)(w + offWh1p);
    float* cws = (float*)(w + offC);
    float* hws = (float*)(w + offH);

    dim3 blk(256);
    wprep_kernel<<<(2048 * 64 + 255) / 256, blk, 0, stream>>>(Wx0, Wx0p, 1, 0);
    wprep_kernel<<<(2048 * 512 + 255) / 256, blk, 0, stream>>>(Wh0, Wh0p, 4, 0);
    wprep_kernel<<<(2048 * 512 + 255) / 256, blk, 0, stream>>>(Wx1, Wx1hp, 4, 1);  // skip flag row
    wprep_kernel<<<(2048 * 512 + 255) / 256, blk, 0, stream>>>(Wh1, Wh1p, 4, 0);

    lstm_main<<<256, 512, 0, stream>>>(x, b0, Wx1, b1, Wlin, blin,
                                       Wx0p, Wh0p, Wx1hp, Wh1p, cws, hws, (float*)d_out);
}